// Round 1
// 183.000 us; speedup vs baseline: 1.0056x; 1.0056x over previous
//
#include <hip/hip_runtime.h>
#include <hip/hip_bf16.h>
#include <math.h>

// dtypes for MFMA
typedef __bf16 bf16x8 __attribute__((ext_vector_type(8)));
typedef float  f32x16 __attribute__((ext_vector_type(16)));

// ---- workspace layout (float offsets) ----
// wfrag : 65536 bf16 (fragment-ready W)          [0, 32768)
// wlast : 256 fp32 (column 256 of conv_w)        [32768, 33024)
// cen   : [128][256] fp32 center pixels          [33024, 65792)
// accA  : [128][256] fp32                        [65792, 98560)
// accX  : [128][256] fp32                        [98560, 131328)
#define WLAST_OFF 32768
#define CEN_OFF   33024
#define ACCA_OFF  65792
#define ACCX_OFF  98560

static __device__ __forceinline__ unsigned f2bf_u(float f) {
    unsigned u = __builtin_bit_cast(unsigned, f);
    return (u + 0x7fffu + ((u >> 16) & 1u)) >> 16;                     // RNE
}
// packed bf16 pair via HW cvt (memcpy: __hip_bfloat162 not trivially copyable)
static __device__ __forceinline__ unsigned pkbf(float a, float b) {
    __hip_bfloat162 h = __float22bfloat162_rn(make_float2(a, b));      // a in low 16
    unsigned u; __builtin_memcpy(&u, &h, 4); return u;
}

// DPP cross-lane add (all-VALU, no LDS pipe)
template<int CTRL, int RM>
static __device__ __forceinline__ float dpp_add(float x) {
    int yi = __builtin_amdgcn_update_dpp(0, __builtin_bit_cast(int, x), CTRL, RM, 0xF, true);
    return x + __builtin_bit_cast(float, yi);
}
// 32-lane (half-wave) sum; valid in lanes 16-31 / 48-63; lane 31/63 used.
static __device__ __forceinline__ float red32(float x) {
    x = dpp_add<0x121, 0xF>(x);   // row_ror:1
    x = dpp_add<0x122, 0xF>(x);   // row_ror:2
    x = dpp_add<0x124, 0xF>(x);   // row_ror:4
    x = dpp_add<0x128, 0xF>(x);   // row_ror:8
    x = dpp_add<0x142, 0xA>(x);   // row_bcast15 into rows 1,3
    return x;
}

// k_init: fragment-ready bf16 W + wlast + center extraction + zero accumulators.
// A-frag (32x32x16): lane l holds A[o = ot*32 + (l&31)][k = S*16 + (l>>5)*8 + j].
__global__ void k_init(const float* __restrict__ x1, const float* __restrict__ x2,
                       const float* __restrict__ conv_w, float* __restrict__ ws) {
    int bk = blockIdx.x;
    int tid = threadIdx.x;
    if (bk < 256) {
        int idx = bk * 256 + tid;                   // 0..65535
        int j  = idx & 7;
        int l  = (idx >> 3) & 63;
        int ot = (idx >> 9) & 7;
        int S  = idx >> 12;                         // 0..15
        int o  = ot * 32 + (l & 31);
        int k  = S * 16 + (l >> 5) * 8 + j;
        ((unsigned short*)ws)[idx] = (unsigned short)f2bf_u(conv_w[o * 257 + k]);
        if (idx < 256) ws[WLAST_OFF + idx] = conv_w[idx * 257 + 256];
        ws[ACCA_OFF + idx] = 0.0f;                  // zeroes accA then accX (65536 floats)
    } else {
        int xb = bk - 256;                          // 0..127: extract centers
        const float* xp = ((xb < 64) ? x1 : x2) + (size_t)(xb & 63) * (256 * 1024);
        ws[CEN_OFF + xb * 256 + tid] = xp[(size_t)tid * 1024 + 528];   // (16,16)
    }
}

// k_main: one block = one image x one 64-hw tile, 8 waves, each wave owns a
// 32-o slice (all 256 o covered). S-major swizzled LDS B-tile: ds_read_b128
// with pure immediate S-offsets (no per-S VALU addr math). Reg- and LDS-lean
// for 3-4 blocks/CU (vs 36% occupancy before).
__global__ __launch_bounds__(512, 6)
void k_main(const float* __restrict__ x1, const float* __restrict__ x2,
            float* __restrict__ ws) {
    int bx = blockIdx.x;               // hw tile: 16 x 64
    int xb = blockIdx.y;               // 0..127
    const float* xp = ((xb < 64) ? x1 : x2) + (size_t)(xb & 63) * (256 * 1024);
    const unsigned short* wfrag = (const unsigned short*)ws;
    float* accA = ws + ACCA_OFF + xb * 256;
    float* accX = ws + ACCX_OFF + xb * 256;
    int hw0 = bx * 64;

    int tid = threadIdx.x;
    int w = tid >> 6;                  // wave 0..7 (owns o = w*32 .. w*32+31)
    int l = tid & 63;
    int lw = l & 31, q = l >> 5;

    // [S][hw][word] bf16-pair tile; word swizzle: phys = logical ^ ((hw>>4)&1)<<2
    // -> writes 2-way (free), b128 reads 4-way (HW floor), S-stride = 2048 B imm.
    __shared__ __align__(16) unsigned sx[16][64][8];   // 32 KB
    __shared__ float sd[64][9];        // dot partials, one col per wave
    __shared__ float swl[256];         // W last column
    __shared__ float dotf[64];

    int hwi = tid & 15, kc = tid >> 4; // thread: hw hwi*4..+3, channels {2kc,2kc+1}+64s

    if (tid < 256) swl[tid] = ws[WLAST_OFF + tid];

    // ---- issue ALL global loads up front: centers (float2, L1/L2-hot) + x ----
    const float* cenp = ws + CEN_OFF + xb * 256;
    float2 cv[4];
    #pragma unroll
    for (int s = 0; s < 4; ++s)
        cv[s] = *(const float2*)(cenp + kc * 2 + 64 * s);
    const float* xst = xp + (size_t)(kc * 2) * 1024 + hw0 + hwi * 4;
    float4 xv[8];
    #pragma unroll
    for (int s = 0; s < 4; ++s) {
        xv[2 * s]     = *(const float4*)(xst + (size_t)(64 * s) * 1024);
        xv[2 * s + 1] = *(const float4*)(xst + (size_t)(64 * s + 1) * 1024);
    }
    __builtin_amdgcn_sched_barrier(0);             // pin: all loads issued before use

    // ---- convert + LDS write + center-dot partials ----
    float dotp[4] = {0.f, 0.f, 0.f, 0.f};
    #pragma unroll
    for (int s = 0; s < 4; ++s) {
        float4 e = xv[2 * s], o4 = xv[2 * s + 1];
        float s0 = cv[s].x, s1 = cv[s].y;
        dotp[0] += e.x * s0 + o4.x * s1;
        dotp[1] += e.y * s0 + o4.y * s1;
        dotp[2] += e.z * s0 + o4.z * s1;
        dotp[3] += e.w * s0 + o4.w * s1;
        int S  = (kc >> 3) + 4 * s;
        int wd = kc & 7;
        float ee[4] = {e.x, e.y, e.z, e.w};
        float oo[4] = {o4.x, o4.y, o4.z, o4.w};
        #pragma unroll
        for (int j = 0; j < 4; ++j) {
            int jj  = (hwi + j) & 3;               // rotate rows (2-way max on write)
            int hwr = hwi * 4 + jj;
            sx[S][hwr][wd ^ (((hwr >> 4) & 1) << 2)] = pkbf(ee[jj], oo[jj]);
        }
    }
    // reduce dot partials across the 4 lanes sharing hwi (lane ^16, ^32)
    #pragma unroll
    for (int j = 0; j < 4; ++j) {
        float v = dotp[j];
        v += __shfl_xor(v, 16, 64);
        v += __shfl_xor(v, 32, 64);
        dotp[j] = v;
    }
    if (l < 16) {
        #pragma unroll
        for (int j = 0; j < 4; ++j) sd[hwi * 4 + j][w] = dotp[j];
    }
    __syncthreads();                               // B1: sx + sd ready

    if (tid < 64) {                                // wave 0 finalizes dot
        float ssum = 0.f;
        #pragma unroll
        for (int k2 = 0; k2 < 8; ++k2) ssum += sd[tid][k2];
        dotf[tid] = ssum * (1.0f / 256.0f);
    }

    // ---- MFMA: 16 K-steps, per wave 2 chains (hw halves), A prefetch dist 1 ----
    f32x16 acc[2];
    #pragma unroll
    for (int e = 0; e < 16; ++e) { acc[0][e] = 0.0f; acc[1][e] = 0.0f; }

    int sig = ((lw >> 4) & 1) << 2;                // same for rows lw and 32+lw
    const unsigned* b0p = &sx[0][lw][(q * 4) ^ sig];
    const unsigned* b1p = &sx[0][32 + lw][(q * 4) ^ sig];
    const unsigned short* ap = wfrag + (size_t)(w * 64 + l) * 8;

    bf16x8 a0 = *(const bf16x8*)(ap);
    #pragma unroll
    for (int S = 0; S < 16; ++S) {
        bf16x8 a1;
        if (S + 1 < 16) a1 = *(const bf16x8*)(ap + (size_t)(S + 1) * 4096);
        bf16x8 b0, b1;
        __builtin_memcpy(&b0, b0p + S * 512, 16);  // byte off = S*2048 (imm)
        __builtin_memcpy(&b1, b1p + S * 512, 16);
        acc[0] = __builtin_amdgcn_mfma_f32_32x32x16_bf16(a0, b0, acc[0], 0, 0, 0);
        acc[1] = __builtin_amdgcn_mfma_f32_32x32x16_bf16(a0, b1, acc[1], 0, 0, 0);
        a0 = a1;
    }
    __syncthreads();                               // B2: dotf ready, sx intact

    // ---- epilogue: z += wlast*dot; sigmoid; x from LDS (bf16); DPP reduce ----
    float dv0 = dotf[lw];
    float dv1 = dotf[32 + lw];
    #pragma unroll
    for (int r = 0; r < 16; ++r) {
        int row = (r & 3) + 8 * (r >> 2) + 4 * q;  // C/D layout (m74/m101)
        int o = w * 32 + row;
        float wl = swl[o];
        float z0 = acc[0][r] + wl * dv0;
        float z1 = acc[1][r] + wl * dv1;
        float a0s = __builtin_amdgcn_rcpf(1.0f + __expf(-z0));
        float a1s = __builtin_amdgcn_rcpf(1.0f + __expf(-z1));
        // x[o][hw0 + jt*32 + lw] from the staged bf16 tile (no global traffic)
        int Si = o >> 4, wd = (o >> 1) & 7;
        unsigned w0 = sx[Si][lw][wd ^ sig];
        unsigned w1 = sx[Si][32 + lw][wd ^ sig];
        float xv0, xv1;
        if (o & 1) {
            xv0 = __builtin_bit_cast(float, w0 & 0xffff0000u);
            xv1 = __builtin_bit_cast(float, w1 & 0xffff0000u);
        } else {
            xv0 = __builtin_bit_cast(float, w0 << 16);
            xv1 = __builtin_bit_cast(float, w1 << 16);
        }
        float sA = red32(a0s + a1s);
        float sX = red32(a0s * xv0 + a1s * xv1);
        if (lw == 31) {                            // lanes 31,63 hold sums
            atomicAdd(&accA[o], sA);
            atomicAdd(&accX[o], sX);
        }
    }
}

// out[b,o] = accX0/(accA0+eps) + accX1/(accA1+eps)
__global__ void k_out(const float* __restrict__ ws, float* __restrict__ out) {
    int idx = blockIdx.x * 256 + threadIdx.x;     // b*256 + o
    int b = idx >> 8, o = idx & 255;
    float a0 = ws[ACCA_OFF + b * 256 + o];
    float p0 = ws[ACCX_OFF + b * 256 + o];
    float a1 = ws[ACCA_OFF + (64 + b) * 256 + o];
    float p1 = ws[ACCX_OFF + (64 + b) * 256 + o];
    out[idx] = p0 / (a0 + 1e-8f) + p1 / (a1 + 1e-8f);
}

extern "C" void kernel_launch(void* const* d_in, const int* in_sizes, int n_in,
                              void* d_out, int out_size, void* d_ws, size_t ws_size,
                              hipStream_t stream) {
    const float* x1     = (const float*)d_in[0];
    const float* x2     = (const float*)d_in[1];
    const float* conv_w = (const float*)d_in[2];
    // d_in[3..6] (caLayer params) are dead: softmax over a size-1 axis == 1.
    float* ws  = (float*)d_ws;
    float* out = (float*)d_out;

    k_init<<<384, 256, 0, stream>>>(x1, x2, conv_w, ws);
    k_main<<<dim3(16, 128), 512, 0, stream>>>(x1, x2, ws);
    k_out<<<64, 256, 0, stream>>>(ws, out);
}

// Round 2
// 178.003 us; speedup vs baseline: 1.0339x; 1.0281x over previous
//
#include <hip/hip_runtime.h>
#include <hip/hip_bf16.h>
#include <math.h>

// dtypes for MFMA
typedef __bf16 bf16x8 __attribute__((ext_vector_type(8)));
typedef float  f32x16 __attribute__((ext_vector_type(16)));

// ---- workspace layout (float offsets) ----
// wfrag : 65536 bf16 (fragment-ready W)          [0, 32768)
// wlast : 256 fp32 (column 256 of conv_w)        [32768, 33024)
// cen   : [128][256] fp32 center pixels          [33024, 65792)
// accA  : [128][256] fp32                        [65792, 98560)
// accX  : [128][256] fp32                        [98560, 131328)
#define WLAST_OFF 32768
#define CEN_OFF   33024
#define ACCA_OFF  65792
#define ACCX_OFF  98560

static __device__ __forceinline__ unsigned f2bf_u(float f) {
    unsigned u = __builtin_bit_cast(unsigned, f);
    return (u + 0x7fffu + ((u >> 16) & 1u)) >> 16;                     // RNE
}
// packed bf16 pair via HW cvt (memcpy: __hip_bfloat162 not trivially copyable)
static __device__ __forceinline__ unsigned pkbf(float a, float b) {
    __hip_bfloat162 h = __float22bfloat162_rn(make_float2(a, b));      // a in low 16
    unsigned u; __builtin_memcpy(&u, &h, 4); return u;
}

// DPP cross-lane add (all-VALU, no LDS pipe)
template<int CTRL, int RM>
static __device__ __forceinline__ float dpp_add(float x) {
    int yi = __builtin_amdgcn_update_dpp(0, __builtin_bit_cast(int, x), CTRL, RM, 0xF, true);
    return x + __builtin_bit_cast(float, yi);
}
// 32-lane (half-wave) sum; valid in lanes 16-31 / 48-63; lane 31/63 used.
static __device__ __forceinline__ float red32(float x) {
    x = dpp_add<0x121, 0xF>(x);   // row_ror:1
    x = dpp_add<0x122, 0xF>(x);   // row_ror:2
    x = dpp_add<0x124, 0xF>(x);   // row_ror:4
    x = dpp_add<0x128, 0xF>(x);   // row_ror:8
    x = dpp_add<0x142, 0xA>(x);   // row_bcast15 into rows 1,3
    return x;
}

// k_init: fragment-ready bf16 W + wlast + center extraction + zero accumulators.
// A-frag (32x32x16): lane l holds A[o = ot*32 + (l&31)][k = S*16 + (l>>5)*8 + j].
__global__ void k_init(const float* __restrict__ x1, const float* __restrict__ x2,
                       const float* __restrict__ conv_w, float* __restrict__ ws) {
    int bk = blockIdx.x;
    int tid = threadIdx.x;
    if (bk < 256) {
        int idx = bk * 256 + tid;                   // 0..65535
        int j  = idx & 7;
        int l  = (idx >> 3) & 63;
        int ot = (idx >> 9) & 7;
        int S  = idx >> 12;                         // 0..15
        int o  = ot * 32 + (l & 31);
        int k  = S * 16 + (l >> 5) * 8 + j;
        ((unsigned short*)ws)[idx] = (unsigned short)f2bf_u(conv_w[o * 257 + k]);
        if (idx < 256) ws[WLAST_OFF + idx] = conv_w[idx * 257 + 256];
        ws[ACCA_OFF + idx] = 0.0f;                  // zeroes accA then accX (65536 floats)
    } else {
        int xb = bk - 256;                          // 0..127: extract centers
        const float* xp = ((xb < 64) ? x1 : x2) + (size_t)(xb & 63) * (256 * 1024);
        ws[CEN_OFF + xb * 256 + tid] = xp[(size_t)tid * 1024 + 528];   // (16,16)
    }
}

// k_main: one block = one image x one 64-hw tile, 8 waves, each wave owns a
// 32-o slice (all 256 o covered). KEY CHANGE vs prev round: all 16 A-fragments
// are preloaded into registers in the up-front load cluster, so the MFMA loop
// has ZERO VMEM ops (prev: 1 global L2 load per K-step covered by only ~40cy
// -> ~200cy stall x16 per wave). A-load latency now hides under convert+B1.
__global__ __launch_bounds__(512, 4)   // cap 128 unified regs -> 2 blocks/CU
void k_main(const float* __restrict__ x1, const float* __restrict__ x2,
            float* __restrict__ ws) {
    int bx = blockIdx.x;               // hw tile: 16 x 64
    int xb = blockIdx.y;               // 0..127
    const float* xp = ((xb < 64) ? x1 : x2) + (size_t)(xb & 63) * (256 * 1024);
    const unsigned short* wfrag = (const unsigned short*)ws;
    float* accA = ws + ACCA_OFF + xb * 256;
    float* accX = ws + ACCX_OFF + xb * 256;
    int hw0 = bx * 64;

    int tid = threadIdx.x;
    int w = tid >> 6;                  // wave 0..7 (owns o = w*32 .. w*32+31)
    int l = tid & 63;
    int lw = l & 31, q = l >> 5;

    // [S][hw][word] bf16-pair tile; word swizzle: phys = logical ^ ((hw>>4)&1)<<2
    // -> writes 2-way (free), b128 reads 4-way (HW floor), S-stride = 2048 B imm.
    __shared__ __align__(16) unsigned sx[16][64][8];   // 32 KB
    __shared__ float sd[64][9];        // dot partials, one col per wave
    __shared__ float swl[256];         // W last column
    __shared__ float dotf[64];

    int hwi = tid & 15, kc = tid >> 4; // thread: hw hwi*4..+3, channels {2kc,2kc+1}+64s

    if (tid < 256) swl[tid] = ws[WLAST_OFF + tid];

    // ---- issue ALL global loads up front: centers + x + ALL 16 A-frags ----
    const float* cenp = ws + CEN_OFF + xb * 256;
    float2 cv[4];
    #pragma unroll
    for (int s = 0; s < 4; ++s)
        cv[s] = *(const float2*)(cenp + kc * 2 + 64 * s);
    const float* xst = xp + (size_t)(kc * 2) * 1024 + hw0 + hwi * 4;
    float4 xv[8];
    #pragma unroll
    for (int s = 0; s < 4; ++s) {
        xv[2 * s]     = *(const float4*)(xst + (size_t)(64 * s) * 1024);
        xv[2 * s + 1] = *(const float4*)(xst + (size_t)(64 * s + 1) * 1024);
    }
    const unsigned short* ap = wfrag + (size_t)(w * 64 + l) * 8;
    bf16x8 A[16];
    #pragma unroll
    for (int S = 0; S < 16; ++S)
        A[S] = *(const bf16x8*)(ap + (size_t)S * 4096);
    __builtin_amdgcn_sched_barrier(0);             // pin: all loads issued before use

    // ---- convert + LDS write + center-dot partials ----
    float dotp[4] = {0.f, 0.f, 0.f, 0.f};
    #pragma unroll
    for (int s = 0; s < 4; ++s) {
        float4 e = xv[2 * s], o4 = xv[2 * s + 1];
        float s0 = cv[s].x, s1 = cv[s].y;
        dotp[0] += e.x * s0 + o4.x * s1;
        dotp[1] += e.y * s0 + o4.y * s1;
        dotp[2] += e.z * s0 + o4.z * s1;
        dotp[3] += e.w * s0 + o4.w * s1;
        int S  = (kc >> 3) + 4 * s;
        int wd = kc & 7;
        float ee[4] = {e.x, e.y, e.z, e.w};
        float oo[4] = {o4.x, o4.y, o4.z, o4.w};
        #pragma unroll
        for (int j = 0; j < 4; ++j) {
            int jj  = (hwi + j) & 3;               // rotate rows (2-way max on write)
            int hwr = hwi * 4 + jj;
            sx[S][hwr][wd ^ (((hwr >> 4) & 1) << 2)] = pkbf(ee[jj], oo[jj]);
        }
    }
    // reduce dot partials across the 4 lanes sharing hwi (lane ^16, ^32)
    #pragma unroll
    for (int j = 0; j < 4; ++j) {
        float v = dotp[j];
        v += __shfl_xor(v, 16, 64);
        v += __shfl_xor(v, 32, 64);
        dotp[j] = v;
    }
    if (l < 16) {
        #pragma unroll
        for (int j = 0; j < 4; ++j) sd[hwi * 4 + j][w] = dotp[j];
    }
    __syncthreads();                               // B1: sx + sd ready

    if (tid < 64) {                                // wave 0 finalizes dot
        float ssum = 0.f;
        #pragma unroll
        for (int k2 = 0; k2 < 8; ++k2) ssum += sd[tid][k2];
        dotf[tid] = ssum * (1.0f / 256.0f);
    }

    // ---- MFMA: 16 K-steps, pure LDS + registers (no VMEM in loop) ----
    f32x16 acc[2];
    #pragma unroll
    for (int e = 0; e < 16; ++e) { acc[0][e] = 0.0f; acc[1][e] = 0.0f; }

    int sig = ((lw >> 4) & 1) << 2;                // same for rows lw and 32+lw
    const unsigned* b0p = &sx[0][lw][(q * 4) ^ sig];
    const unsigned* b1p = &sx[0][32 + lw][(q * 4) ^ sig];

    #pragma unroll
    for (int S = 0; S < 16; ++S) {
        bf16x8 b0, b1;
        __builtin_memcpy(&b0, b0p + S * 512, 16);  // byte off = S*2048 (imm)
        __builtin_memcpy(&b1, b1p + S * 512, 16);
        acc[0] = __builtin_amdgcn_mfma_f32_32x32x16_bf16(A[S], b0, acc[0], 0, 0, 0);
        acc[1] = __builtin_amdgcn_mfma_f32_32x32x16_bf16(A[S], b1, acc[1], 0, 0, 0);
    }
    __syncthreads();                               // B2: dotf ready, sx intact

    // ---- epilogue: z += wlast*dot; sigmoid; x from LDS (bf16); DPP reduce ----
    float dv0 = dotf[lw];
    float dv1 = dotf[32 + lw];
    #pragma unroll
    for (int r = 0; r < 16; ++r) {
        int row = (r & 3) + 8 * (r >> 2) + 4 * q;  // C/D layout (m74/m101)
        int o = w * 32 + row;
        float wl = swl[o];
        float z0 = acc[0][r] + wl * dv0;
        float z1 = acc[1][r] + wl * dv1;
        float a0s = __builtin_amdgcn_rcpf(1.0f + __expf(-z0));
        float a1s = __builtin_amdgcn_rcpf(1.0f + __expf(-z1));
        // x[o][hw0 + jt*32 + lw] from the staged bf16 tile (no global traffic)
        int Si = o >> 4, wd = (o >> 1) & 7;
        unsigned w0 = sx[Si][lw][wd ^ sig];
        unsigned w1 = sx[Si][32 + lw][wd ^ sig];
        float xv0, xv1;
        if (o & 1) {
            xv0 = __builtin_bit_cast(float, w0 & 0xffff0000u);
            xv1 = __builtin_bit_cast(float, w1 & 0xffff0000u);
        } else {
            xv0 = __builtin_bit_cast(float, w0 << 16);
            xv1 = __builtin_bit_cast(float, w1 << 16);
        }
        float sA = red32(a0s + a1s);
        float sX = red32(a0s * xv0 + a1s * xv1);
        if (lw == 31) {                            // lanes 31,63 hold sums
            atomicAdd(&accA[o], sA);
            atomicAdd(&accX[o], sX);
        }
    }
}

// out[b,o] = accX0/(accA0+eps) + accX1/(accA1+eps)
__global__ void k_out(const float* __restrict__ ws, float* __restrict__ out) {
    int idx = blockIdx.x * 256 + threadIdx.x;     // b*256 + o
    int b = idx >> 8, o = idx & 255;
    float a0 = ws[ACCA_OFF + b * 256 + o];
    float p0 = ws[ACCX_OFF + b * 256 + o];
    float a1 = ws[ACCA_OFF + (64 + b) * 256 + o];
    float p1 = ws[ACCX_OFF + (64 + b) * 256 + o];
    out[idx] = p0 / (a0 + 1e-8f) + p1 / (a1 + 1e-8f);
}

extern "C" void kernel_launch(void* const* d_in, const int* in_sizes, int n_in,
                              void* d_out, int out_size, void* d_ws, size_t ws_size,
                              hipStream_t stream) {
    const float* x1     = (const float*)d_in[0];
    const float* x2     = (const float*)d_in[1];
    const float* conv_w = (const float*)d_in[2];
    // d_in[3..6] (caLayer params) are dead: softmax over a size-1 axis == 1.
    float* ws  = (float*)d_ws;
    float* out = (float*)d_out;

    k_init<<<384, 256, 0, stream>>>(x1, x2, conv_w, ws);
    k_main<<<dim3(16, 128), 512, 0, stream>>>(x1, x2, ws);
    k_out<<<64, 256, 0, stream>>>(ws, out);
}

// Round 3
// 163.877 us; speedup vs baseline: 1.1230x; 1.0862x over previous
//
#include <hip/hip_runtime.h>
#include <hip/hip_bf16.h>
#include <math.h>

// dtypes for MFMA
typedef __bf16 bf16x8 __attribute__((ext_vector_type(8)));
typedef float  f32x16 __attribute__((ext_vector_type(16)));

// ---- workspace layout (float offsets) ----
// wfrag : 65536 bf16 (fragment-ready W)          [0, 32768)
// wlast : 256 fp32 (column 256 of conv_w)        [32768, 33024)
// accA  : [128][256] fp32                        [65792, 98560)
// accX  : [128][256] fp32                        [98560, 131328)
#define WLAST_OFF 32768
#define ACCA_OFF  65792
#define ACCX_OFF  98560

static __device__ __forceinline__ unsigned f2bf_u(float f) {
    unsigned u = __builtin_bit_cast(unsigned, f);
    return (u + 0x7fffu + ((u >> 16) & 1u)) >> 16;                     // RNE
}
// packed bf16 pair via HW cvt (memcpy: __hip_bfloat162 not trivially copyable)
static __device__ __forceinline__ unsigned pkbf(float a, float b) {
    __hip_bfloat162 h = __float22bfloat162_rn(make_float2(a, b));      // a in low 16
    unsigned u; __builtin_memcpy(&u, &h, 4); return u;
}

// Barrier WITHOUT vmcnt drain: LDS produced by reg->ds_write only (no
// global_load_lds), so lgkmcnt(0)+s_barrier is sufficient for LDS visibility
// while our prefetch global->reg loads stay in flight across the barrier.
static __device__ __forceinline__ void barrier_lds() {
    asm volatile("s_waitcnt lgkmcnt(0)\n\ts_barrier" ::: "memory");
}

// DPP cross-lane add (all-VALU, no LDS pipe)
template<int CTRL, int RM>
static __device__ __forceinline__ float dpp_add(float x) {
    int yi = __builtin_amdgcn_update_dpp(0, __builtin_bit_cast(int, x), CTRL, RM, 0xF, true);
    return x + __builtin_bit_cast(float, yi);
}
// 32-lane (half-wave) sum; valid in lanes 16-31 / 48-63; lane 31/63 used.
static __device__ __forceinline__ float red32(float x) {
    x = dpp_add<0x121, 0xF>(x);   // row_ror:1
    x = dpp_add<0x122, 0xF>(x);   // row_ror:2
    x = dpp_add<0x124, 0xF>(x);   // row_ror:4
    x = dpp_add<0x128, 0xF>(x);   // row_ror:8
    x = dpp_add<0x142, 0xA>(x);   // row_bcast15 into rows 1,3
    return x;
}

// k_init: fragment-ready bf16 W + wlast + zero accumulators (needed each launch:
// k_main accumulates via atomics).
// A-frag (32x32x16): lane l holds A[o = ot*32 + (l&31)][k = S*16 + (l>>5)*8 + j].
__global__ void k_init(const float* __restrict__ conv_w, float* __restrict__ ws) {
    int bk = blockIdx.x;
    int tid = threadIdx.x;
    int idx = bk * 256 + tid;                   // 0..65535
    int j  = idx & 7;
    int l  = (idx >> 3) & 63;
    int ot = (idx >> 9) & 7;
    int S  = idx >> 12;                         // 0..15
    int o  = ot * 32 + (l & 31);
    int k  = S * 16 + (l >> 5) * 8 + j;
    ((unsigned short*)ws)[idx] = (unsigned short)f2bf_u(conv_w[o * 257 + k]);
    if (idx < 256) ws[WLAST_OFF + idx] = conv_w[idx * 257 + 256];
    ws[ACCA_OFF + idx] = 0.0f;                  // zeroes accA then accX (65536 floats)
}

// k_main: persistent-ish blocks. 256 blocks = 1/CU; block = (image xb, hw-half).
// 8 software-pipelined chunks of 64 hw: prefetch chunk t+1's x (global->reg)
// while chunk t runs convert->MFMA->epilogue. Per-wave A-frags (o slice
// w*32..+31) and per-r sigmoid sums live in registers across all chunks;
// DPP reduce + atomics happen ONCE per block (8x less than before).
__global__ __launch_bounds__(512, 2)   // ~195 VGPR; 8 waves/CU by design
void k_main(const float* __restrict__ x1, const float* __restrict__ x2,
            float* __restrict__ ws) {
    int bx = blockIdx.x;               // 0..255
    int xb = bx >> 1;                  // image 0..127
    int half = bx & 1;                 // hw half: 512 positions
    const float* xpi = ((xb < 64) ? x1 : x2) + (size_t)(xb & 63) * (256 * 1024);
    const unsigned short* wfrag = (const unsigned short*)ws;
    float* accA = ws + ACCA_OFF + xb * 256;
    float* accX = ws + ACCX_OFF + xb * 256;

    int tid = threadIdx.x;
    int w = tid >> 6;                  // wave 0..7 (owns o = w*32 .. w*32+31)
    int l = tid & 63;
    int lw = l & 31, q = l >> 5;

    // [S][hw][word] bf16-pair tile; word swizzle: phys = logical ^ ((hw>>4)&1)<<2
    // -> writes 2-way (free), b128 reads 4-way (HW floor), S-stride = 2048 B imm.
    __shared__ __align__(16) unsigned sx[16][64][8];   // 32 KB (single buffer)
    __shared__ float sd[64][9];        // dot partials, one col per wave
    __shared__ float swl[256];         // W last column
    __shared__ float scen[256];        // this image's center pixels
    __shared__ float dotf[64];

    int hwi = tid & 15, kc = tid >> 4; // thread: hw hwi*4..+3, channels {2kc,2kc+1}+64s

    // ---- prologue: centers + wlast -> LDS; A-frags -> regs; chunk-0 x -> regs ----
    float cenv = 0.f, wlv = 0.f;
    if (tid < 256) {
        cenv = xpi[(size_t)tid * 1024 + 528];          // x[tid][16][16]
        wlv  = ws[WLAST_OFF + tid];
    }
    const unsigned short* ap = wfrag + (size_t)(w * 64 + l) * 8;
    bf16x8 A[16];
    #pragma unroll
    for (int S = 0; S < 16; ++S)
        A[S] = *(const bf16x8*)(ap + (size_t)S * 4096);

    const float* xbase = xpi + half * 512 + (size_t)(kc * 2) * 1024 + hwi * 4;
    float4 xv[8];
    #pragma unroll
    for (int s = 0; s < 4; ++s) {
        xv[2 * s]     = *(const float4*)(xbase + (size_t)(64 * s) * 1024);
        xv[2 * s + 1] = *(const float4*)(xbase + (size_t)(64 * s + 1) * 1024);
    }
    if (tid < 256) { scen[tid] = cenv; swl[tid] = wlv; }
    barrier_lds();                                     // scen/swl visible

    int sig = ((lw >> 4) & 1) << 2;                    // same for rows lw, 32+lw
    const unsigned* b0p = &sx[0][lw][(q * 4) ^ sig];
    const unsigned* b1p = &sx[0][32 + lw][(q * 4) ^ sig];

    float sA[16], sX[16];
    #pragma unroll
    for (int r = 0; r < 16; ++r) { sA[r] = 0.f; sX[r] = 0.f; }

    #pragma unroll 1
    for (int t = 0; t < 8; ++t) {
        if (t) barrier_lds();                          // B3: epilogue done with sx

        // ---- convert chunk t + LDS write + center-dot partials ----
        float dotp[4] = {0.f, 0.f, 0.f, 0.f};
        #pragma unroll
        for (int s = 0; s < 4; ++s) {
            float4 e = xv[2 * s], o4 = xv[2 * s + 1];
            int c = kc * 2 + 64 * s;
            float s0 = scen[c], s1 = scen[c + 1];
            dotp[0] += e.x * s0 + o4.x * s1;
            dotp[1] += e.y * s0 + o4.y * s1;
            dotp[2] += e.z * s0 + o4.z * s1;
            dotp[3] += e.w * s0 + o4.w * s1;
            int S  = (kc >> 3) + 4 * s;
            int wd = kc & 7;
            float ee[4] = {e.x, e.y, e.z, e.w};
            float oo[4] = {o4.x, o4.y, o4.z, o4.w};
            #pragma unroll
            for (int j = 0; j < 4; ++j) {
                int jj  = (hwi + j) & 3;               // rotate rows (2-way write)
                int hwr = hwi * 4 + jj;
                sx[S][hwr][wd ^ (((hwr >> 4) & 1) << 2)] = pkbf(ee[jj], oo[jj]);
            }
        }
        // ---- prefetch chunk t+1 (stays in flight across the barriers) ----
        if (t < 7) {
            const float* xn = xbase + (t + 1) * 64;
            #pragma unroll
            for (int s = 0; s < 4; ++s) {
                xv[2 * s]     = *(const float4*)(xn + (size_t)(64 * s) * 1024);
                xv[2 * s + 1] = *(const float4*)(xn + (size_t)(64 * s + 1) * 1024);
            }
        }
        // reduce dot partials across the 4 lanes sharing hwi (lane ^16, ^32)
        #pragma unroll
        for (int j = 0; j < 4; ++j) {
            float v = dotp[j];
            v += __shfl_xor(v, 16, 64);
            v += __shfl_xor(v, 32, 64);
            dotp[j] = v;
        }
        if (l < 16) {
            #pragma unroll
            for (int j = 0; j < 4; ++j) sd[hwi * 4 + j][w] = dotp[j];
        }
        barrier_lds();                                 // B1: sx + sd ready

        if (tid < 64) {                                // wave 0 finalizes dot
            float ssum = 0.f;
            #pragma unroll
            for (int k2 = 0; k2 < 8; ++k2) ssum += sd[tid][k2];
            dotf[tid] = ssum * (1.0f / 256.0f);
        }

        // ---- MFMA: 16 K-steps, pure LDS + registers ----
        f32x16 acc0, acc1;
        #pragma unroll
        for (int e = 0; e < 16; ++e) { acc0[e] = 0.0f; acc1[e] = 0.0f; }
        #pragma unroll
        for (int S = 0; S < 16; ++S) {
            bf16x8 b0, b1;
            __builtin_memcpy(&b0, b0p + S * 512, 16);  // byte off = S*2048 (imm)
            __builtin_memcpy(&b1, b1p + S * 512, 16);
            acc0 = __builtin_amdgcn_mfma_f32_32x32x16_bf16(A[S], b0, acc0, 0, 0, 0);
            acc1 = __builtin_amdgcn_mfma_f32_32x32x16_bf16(A[S], b1, acc1, 0, 0, 0);
        }
        barrier_lds();                                 // B2: dotf ready, sx intact

        // ---- epilogue chunk t: sigmoid + accumulate into sA/sX regs ----
        float dv0 = dotf[lw];
        float dv1 = dotf[32 + lw];
        #pragma unroll
        for (int r = 0; r < 16; ++r) {
            int row = (r & 3) + 8 * (r >> 2) + 4 * q;  // C/D layout (m74/m101)
            int o = w * 32 + row;
            float wl = swl[o];
            float z0 = acc0[r] + wl * dv0;
            float z1 = acc1[r] + wl * dv1;
            float a0s = __builtin_amdgcn_rcpf(1.0f + __expf(-z0));
            float a1s = __builtin_amdgcn_rcpf(1.0f + __expf(-z1));
            // x[o][hw] from the staged bf16 tile (no global traffic)
            int Si = o >> 4, wd = (o >> 1) & 7;
            unsigned w0 = sx[Si][lw][wd ^ sig];
            unsigned w1 = sx[Si][32 + lw][wd ^ sig];
            float xv0, xv1;
            if (o & 1) {
                xv0 = __builtin_bit_cast(float, w0 & 0xffff0000u);
                xv1 = __builtin_bit_cast(float, w1 & 0xffff0000u);
            } else {
                xv0 = __builtin_bit_cast(float, w0 << 16);
                xv1 = __builtin_bit_cast(float, w1 << 16);
            }
            sA[r] += a0s + a1s;
            sX[r] += a0s * xv0 + a1s * xv1;
        }
    }

    // ---- final: one DPP reduce + one atomic pair per o for the whole block ----
    #pragma unroll
    for (int r = 0; r < 16; ++r) {
        int row = (r & 3) + 8 * (r >> 2) + 4 * q;
        int o = w * 32 + row;
        float rA = red32(sA[r]);
        float rX = red32(sX[r]);
        if (lw == 31) {                                // lanes 31,63 hold sums
            atomicAdd(&accA[o], rA);
            atomicAdd(&accX[o], rX);
        }
    }
}

// out[b,o] = accX0/(accA0+eps) + accX1/(accA1+eps)
__global__ void k_out(const float* __restrict__ ws, float* __restrict__ out) {
    int idx = blockIdx.x * 256 + threadIdx.x;     // b*256 + o
    int b = idx >> 8, o = idx & 255;
    float a0 = ws[ACCA_OFF + b * 256 + o];
    float p0 = ws[ACCX_OFF + b * 256 + o];
    float a1 = ws[ACCA_OFF + (64 + b) * 256 + o];
    float p1 = ws[ACCX_OFF + (64 + b) * 256 + o];
    out[idx] = p0 / (a0 + 1e-8f) + p1 / (a1 + 1e-8f);
}

extern "C" void kernel_launch(void* const* d_in, const int* in_sizes, int n_in,
                              void* d_out, int out_size, void* d_ws, size_t ws_size,
                              hipStream_t stream) {
    const float* x1     = (const float*)d_in[0];
    const float* x2     = (const float*)d_in[1];
    const float* conv_w = (const float*)d_in[2];
    // d_in[3..6] (caLayer params) are dead: softmax over a size-1 axis == 1.
    float* ws  = (float*)d_ws;
    float* out = (float*)d_out;

    k_init<<<256, 256, 0, stream>>>(conv_w, ws);
    k_main<<<256, 512, 0, stream>>>(x1, x2, ws);
    k_out<<<64, 256, 0, stream>>>(ws, out);
}